// Round 1
// baseline (912.318 us; speedup 1.0000x reference)
//
#include <hip/hip_runtime.h>
#include <hip/hip_bf16.h>

#define N_NODES 20000
#define N_EDGES 100000
#define N_LAYERS 25
#define NPAD 20096   // 157*128
#define EPS_BN 1e-5f

typedef short short8 __attribute__((ext_vector_type(8)));
typedef float floatx4 __attribute__((ext_vector_type(4)));

// ---------------- CSR build ----------------
__global__ __launch_bounds__(256) void count_kernel(const int* __restrict__ ei,
                                                    int* __restrict__ cnt) {
  int idx = blockIdx.x * 256 + threadIdx.x;
  if (idx >= N_LAYERS * N_EDGES) return;
  int l = idx / N_EDGES, e = idx - l * N_EDGES;
  int dst = ei[(size_t)l * 2 * N_EDGES + N_EDGES + e];
  atomicAdd(&cnt[l * (N_NODES + 1) + dst], 1);
}

__global__ __launch_bounds__(256) void scan_kernel(int* __restrict__ rowptr,
                                                   int* __restrict__ fillptr) {
  int l = blockIdx.x, t = threadIdx.x;
  __shared__ int sd[256];
  __shared__ int carry_s;
  if (t == 0) carry_s = 0;
  __syncthreads();
  int base = l * (N_NODES + 1);
  for (int c0 = 0; c0 < N_NODES; c0 += 256) {
    int i = c0 + t;
    int v = (i < N_NODES) ? rowptr[base + i] : 0;
    sd[t] = v;
    __syncthreads();
#pragma unroll
    for (int off = 1; off < 256; off <<= 1) {
      int xv = (t >= off) ? sd[t - off] : 0;
      __syncthreads();
      sd[t] += xv;
      __syncthreads();
    }
    int excl = sd[t] - v;
    int val = carry_s + excl;
    if (i < N_NODES) { rowptr[base + i] = val; fillptr[l * N_NODES + i] = val; }
    int tot = sd[255];
    __syncthreads();
    if (t == 0) carry_s += tot;
    __syncthreads();
  }
  if (t == 0) rowptr[base + N_NODES] = carry_s;
}

__global__ __launch_bounds__(256) void fill_kernel(const int* __restrict__ ei,
                                                   const float* __restrict__ ew,
                                                   int* __restrict__ fillptr,
                                                   int* __restrict__ ssrc,
                                                   float* __restrict__ sw) {
  int idx = blockIdx.x * 256 + threadIdx.x;
  if (idx >= N_LAYERS * N_EDGES) return;
  int l = idx / N_EDGES, e = idx - l * N_EDGES;
  int src = ei[(size_t)l * 2 * N_EDGES + e];
  int dst = ei[(size_t)l * 2 * N_EDGES + N_EDGES + e];
  int pos = atomicAdd(&fillptr[l * N_NODES + dst], 1);
  ssrc[(size_t)l * N_EDGES + pos] = src;
  sw[(size_t)l * N_EDGES + pos] = ew[(size_t)l * N_EDGES + e];
}

// ---------------- fused GAT layer (1 wave per (layer,node)) ----------------
__global__ __launch_bounds__(256) void attn_kernel(
    const float* __restrict__ x, const int* __restrict__ rowptr,
    const int* __restrict__ ssrc, const float* __restrict__ sw,
    const float* __restrict__ Wl, const float* __restrict__ bl,
    const float* __restrict__ Wr, const float* __restrict__ br,
    const float* __restrict__ We, const float* __restrict__ att,
    const float* __restrict__ cbias, float* __restrict__ out_pre) {
  int wid = blockIdx.x * 4 + (threadIdx.x >> 6);
  int lane = threadIdx.x & 63;
  int l = wid / N_NODES, n = wid - l * N_NODES;

  float wlv[5], wrv[5];
#pragma unroll
  for (int k = 0; k < 5; k++) {
    wlv[k] = Wl[(l * 5 + k) * 64 + lane];
    wrv[k] = Wr[(l * 5 + k) * 64 + lane];
  }
  float blv = bl[l * 64 + lane], brv = br[l * 64 + lane];
  float wev = We[l * 64 + lane];
  float attv = att[l * 64 + lane];

  float xn[5];
#pragma unroll
  for (int k = 0; k < 5; k++) xn[k] = x[n * 5 + k];
  float xrn = brv, xln = blv;
#pragma unroll
  for (int k = 0; k < 5; k++) { xrn += xn[k] * wrv[k]; xln += xn[k] * wlv[k]; }

  int start = __builtin_amdgcn_readfirstlane(rowptr[l * (N_NODES + 1) + n]);
  int end   = __builtin_amdgcn_readfirstlane(rowptr[l * (N_NODES + 1) + n + 1]);
  int cnt = end - start;

  float m = -1e30f, s = 0.f, acc = 0.f, ewsum = 0.f;
  for (int e = start; e < end; e++) {
    int src = __builtin_amdgcn_readfirstlane(ssrc[(size_t)l * N_EDGES + e]);
    float w = sw[(size_t)l * N_EDGES + e];
    float xls = blv;
#pragma unroll
    for (int k = 0; k < 5; k++) xls += x[src * 5 + k] * wlv[k];
    float eh = xls + xrn + w * wev;
    eh = eh > 0.f ? eh : 0.2f * eh;
    float p = eh * attv;
    p += __shfl_xor(p, 16);
    p += __shfl_xor(p, 8);
    p += __shfl_xor(p, 4);
    p += __shfl_xor(p, 2);
    p += __shfl_xor(p, 1);
    float mn = fmaxf(m, p);
    float corr = __expf(m - mn);
    float pe = __expf(p - mn);
    s = s * corr + pe;
    acc = acc * corr + xls * pe;
    m = mn;
    ewsum += w;
  }
  // self loop: attr = mean of incoming edge attrs
  {
    float w = ewsum / fmaxf((float)cnt, 1.f);
    float eh = xln + xrn + w * wev;
    eh = eh > 0.f ? eh : 0.2f * eh;
    float p = eh * attv;
    p += __shfl_xor(p, 16);
    p += __shfl_xor(p, 8);
    p += __shfl_xor(p, 4);
    p += __shfl_xor(p, 2);
    p += __shfl_xor(p, 1);
    float mn = fmaxf(m, p);
    float corr = __expf(m - mn);
    float pe = __expf(p - mn);
    s = s * corr + pe;
    acc = acc * corr + xln * pe;
  }
  float outv = acc / (s * (float)(cnt + 1));
  float o2 = outv + __shfl_xor(outv, 32);
  if (lane < 32)
    out_pre[((size_t)l * N_NODES + n) * 32 + lane] = 0.5f * o2 + cbias[l * 32 + lane];
}

// ---------------- BatchNorm stats ----------------
__global__ __launch_bounds__(256) void stats_kernel(const float* __restrict__ out_pre,
                                                    float* __restrict__ gsum,
                                                    float* __restrict__ gsumsq) {
  int l = blockIdx.x >> 4, chunk = blockIdx.x & 15;
  int t = threadIdx.x;
  int c = t & 31, nsub = t >> 5;
  int n0 = chunk * 1250;
  float s1 = 0.f, s2 = 0.f;
  for (int n = n0 + nsub; n < n0 + 1250; n += 8) {
    float v = out_pre[((size_t)l * N_NODES + n) * 32 + c];
    s1 += v; s2 += v * v;
  }
  __shared__ float l1[256], l2[256];
  l1[t] = s1; l2[t] = s2;
  __syncthreads();
  for (int off = 128; off >= 32; off >>= 1) {
    if (t < off) { l1[t] += l1[t + off]; l2[t] += l2[t + off]; }
    __syncthreads();
  }
  if (t < 32) {
    atomicAdd(&gsum[l * 32 + t], l1[t]);
    atomicAdd(&gsumsq[l * 32 + t], l2[t]);
  }
}

// ---------------- normalize + leaky relu -> bf16 [L][NPAD][32] ----------------
__global__ __launch_bounds__(256) void norm_kernel(const float* __restrict__ out_pre,
                                                   const float* __restrict__ gsum,
                                                   const float* __restrict__ gsumsq,
                                                   const float* __restrict__ gamma,
                                                   const float* __restrict__ beta,
                                                   __hip_bfloat16* __restrict__ hn) {
  int idx = blockIdx.x * 256 + threadIdx.x;  // < 25*20000*32
  int l = idx / (N_NODES * 32);
  int rem = idx - l * (N_NODES * 32);
  int n = rem >> 5, c = rem & 31;
  float mu = gsum[l * 32 + c] * (1.f / N_NODES);
  float var = gsumsq[l * 32 + c] * (1.f / N_NODES) - mu * mu;
  float v = out_pre[idx];
  v = gamma[l * 32 + c] * (v - mu) * rsqrtf(var + EPS_BN) + beta[l * 32 + c];
  v = v > 0.f ? v : 0.01f * v;
  hn[((size_t)l * NPAD + n) * 32 + c] = (__hip_bfloat16)v;
}

// ---------------- W1 -> bf16 transposed [896][800] ----------------
__global__ void w1t_kernel(const float* __restrict__ W1, __hip_bfloat16* __restrict__ W1bT) {
  __shared__ float tile[32][33];
  int j0 = blockIdx.x * 32, k0 = blockIdx.y * 32;
  int tx = threadIdx.x, ty = threadIdx.y;  // (32,8)
#pragma unroll
  for (int i = 0; i < 4; i++) {
    int k = k0 + ty + i * 8, j = j0 + tx;
    tile[ty + i * 8][tx] = (j < 800) ? W1[k * 800 + j] : 0.f;
  }
  __syncthreads();
#pragma unroll
  for (int i = 0; i < 4; i++) {
    int j = j0 + ty + i * 8, k = k0 + tx;
    W1bT[(size_t)j * 800 + k] = (__hip_bfloat16)tile[tx][ty + i * 8];
  }
}

// ---------------- GEMM1: h[NPAD x 800] @ W1 -> relu -> bf16 h1 ----------------
__global__ __launch_bounds__(256) void gemm1_kernel(const short* __restrict__ hn,
                                                    const short* __restrict__ W1bT,
                                                    const float* __restrict__ b1,
                                                    __hip_bfloat16* __restrict__ h1b) {
  __shared__ __align__(16) short As[128 * 40];
  __shared__ __align__(16) short Bs[128 * 40];
  int t = threadIdx.x;
  int n0 = blockIdx.x * 128, m0 = blockIdx.y * 128;
  int wave = t >> 6, lane = t & 63;
  int wr = wave >> 1, wc = wave & 1;
  int mrow = lane & 15, quad = lane >> 4;
  floatx4 acc[4][4];
#pragma unroll
  for (int i = 0; i < 4; i++)
#pragma unroll
    for (int j = 0; j < 4; j++) acc[i][j] = (floatx4){0.f, 0.f, 0.f, 0.f};

  for (int kt = 0; kt < 25; kt++) {
#pragma unroll
    for (int i = 0; i < 2; i++) {
      int q = t + i * 256;
      int r = q >> 2, sub = q & 3;
      const int4* gA = (const int4*)(hn + ((size_t)kt * NPAD + m0 + r) * 32 + sub * 8);
      *(int4*)(&As[r * 40 + sub * 8]) = *gA;
      const int4* gB = (const int4*)(W1bT + (size_t)(n0 + r) * 800 + kt * 32 + sub * 8);
      *(int4*)(&Bs[r * 40 + sub * 8]) = *gB;
    }
    __syncthreads();
    short8 af[4], bfr[4];
#pragma unroll
    for (int i = 0; i < 4; i++)
      af[i] = *(const short8*)(&As[(wr * 64 + i * 16 + mrow) * 40 + quad * 8]);
#pragma unroll
    for (int j = 0; j < 4; j++)
      bfr[j] = *(const short8*)(&Bs[(wc * 64 + j * 16 + mrow) * 40 + quad * 8]);
#pragma unroll
    for (int i = 0; i < 4; i++)
#pragma unroll
      for (int j = 0; j < 4; j++)
        acc[i][j] = __builtin_amdgcn_mfma_f32_16x16x32_bf16(af[i], bfr[j], acc[i][j], 0, 0, 0);
    __syncthreads();
  }

#pragma unroll
  for (int i = 0; i < 4; i++) {
#pragma unroll
    for (int j = 0; j < 4; j++) {
#pragma unroll
      for (int r = 0; r < 4; r++) {
        int row = m0 + wr * 64 + i * 16 + quad * 4 + r;
        int col = n0 + wc * 64 + j * 16 + mrow;
        if (col < 800) {
          float v = acc[i][j][r] + b1[col];
          v = fmaxf(v, 0.f);
          h1b[(size_t)row * 800 + col] = (__hip_bfloat16)v;
        }
      }
    }
  }
}

// ---------------- GEMM2: h1[20000 x 800] @ W2[800 x 5] + b2 ----------------
__global__ __launch_bounds__(256) void gemm2_kernel(const __hip_bfloat16* __restrict__ h1b,
                                                    const float* __restrict__ W2,
                                                    const float* __restrict__ b2,
                                                    float* __restrict__ out) {
  int wid = blockIdx.x * 4 + (threadIdx.x >> 6);
  int lane = threadIdx.x & 63;
  if (wid >= N_NODES) return;
  const __hip_bfloat16* row = h1b + (size_t)wid * 800;
  float a[5] = {0.f, 0.f, 0.f, 0.f, 0.f};
  for (int k = lane * 2; k < 800; k += 128) {
    float a0 = (float)row[k], a1 = (float)row[k + 1];
#pragma unroll
    for (int j = 0; j < 5; j++) a[j] += a0 * W2[k * 5 + j] + a1 * W2[(k + 1) * 5 + j];
  }
#pragma unroll
  for (int j = 0; j < 5; j++) {
    a[j] += __shfl_xor(a[j], 32);
    a[j] += __shfl_xor(a[j], 16);
    a[j] += __shfl_xor(a[j], 8);
    a[j] += __shfl_xor(a[j], 4);
    a[j] += __shfl_xor(a[j], 2);
    a[j] += __shfl_xor(a[j], 1);
  }
  if (lane == 0) {
#pragma unroll
    for (int j = 0; j < 5; j++) out[wid * 5 + j] = a[j] + b2[j];
  }
}

extern "C" void kernel_launch(void* const* d_in, const int* in_sizes, int n_in,
                              void* d_out, int out_size, void* d_ws, size_t ws_size,
                              hipStream_t stream) {
  const float* x    = (const float*)d_in[0];
  const int*   ei   = (const int*)d_in[1];
  const float* ew   = (const float*)d_in[2];
  const float* Wl   = (const float*)d_in[3];
  const float* bl   = (const float*)d_in[4];
  const float* Wr   = (const float*)d_in[5];
  const float* br   = (const float*)d_in[6];
  const float* We   = (const float*)d_in[7];
  const float* att  = (const float*)d_in[8];
  const float* cb   = (const float*)d_in[9];
  const float* gam  = (const float*)d_in[10];
  const float* bet  = (const float*)d_in[11];
  const float* W1   = (const float*)d_in[12];
  const float* b1   = (const float*)d_in[13];
  const float* W2   = (const float*)d_in[14];
  const float* b2   = (const float*)d_in[15];

  char* ws = (char*)d_ws;
  size_t off = 0;
  auto alloc = [&](size_t bytes) {
    void* p = ws + off;
    off = (off + bytes + 255) & ~(size_t)255;
    return p;
  };
  int* rowptr  = (int*)alloc((size_t)N_LAYERS * (N_NODES + 1) * 4);
  int* fillptr = (int*)alloc((size_t)N_LAYERS * N_NODES * 4);
  int* ssrc    = (int*)alloc((size_t)N_LAYERS * N_EDGES * 4);
  float* swt   = (float*)alloc((size_t)N_LAYERS * N_EDGES * 4);
  float* out_pre = (float*)alloc((size_t)N_LAYERS * N_NODES * 32 * 4);
  float* gsum   = (float*)alloc(N_LAYERS * 32 * 4);
  float* gsumsq = (float*)alloc(N_LAYERS * 32 * 4);
  __hip_bfloat16* hn  = (__hip_bfloat16*)alloc((size_t)N_LAYERS * NPAD * 32 * 2);
  __hip_bfloat16* w1t = (__hip_bfloat16*)alloc((size_t)896 * 800 * 2);
  __hip_bfloat16* h1b = (__hip_bfloat16*)out_pre;  // alias: out_pre dead after norm_kernel

  hipMemsetAsync(rowptr, 0, (size_t)N_LAYERS * (N_NODES + 1) * 4, stream);
  hipMemsetAsync(gsum, 0, N_LAYERS * 32 * 4, stream);
  hipMemsetAsync(gsumsq, 0, N_LAYERS * 32 * 4, stream);

  int ecnt = N_LAYERS * N_EDGES;
  count_kernel<<<(ecnt + 255) / 256, 256, 0, stream>>>(ei, rowptr);
  scan_kernel<<<N_LAYERS, 256, 0, stream>>>(rowptr, fillptr);
  fill_kernel<<<(ecnt + 255) / 256, 256, 0, stream>>>(ei, ew, fillptr, ssrc, swt);
  attn_kernel<<<(N_LAYERS * N_NODES) / 4, 256, 0, stream>>>(
      x, rowptr, ssrc, swt, Wl, bl, Wr, br, We, att, cb, out_pre);
  stats_kernel<<<N_LAYERS * 16, 256, 0, stream>>>(out_pre, gsum, gsumsq);
  norm_kernel<<<(N_LAYERS * N_NODES * 32) / 256, 256, 0, stream>>>(
      out_pre, gsum, gsumsq, gam, bet, hn);
  w1t_kernel<<<dim3(28, 25), dim3(32, 8), 0, stream>>>(W1, w1t);
  gemm1_kernel<<<dim3(7, 157), 256, 0, stream>>>(
      (const short*)hn, (const short*)w1t, b1, h1b);
  gemm2_kernel<<<5000, 256, 0, stream>>>(h1b, W2, b2, (float*)d_out);
}

// Round 2
// 833.993 us; speedup vs baseline: 1.0939x; 1.0939x over previous
//
#include <hip/hip_runtime.h>
#include <hip/hip_bf16.h>

#define N_NODES 20000
#define N_EDGES 100000
#define N_LAYERS 25
#define NPAD 20096   // 157*128
#define EPS_BN 1e-5f
#define LOG2E 1.44269504088896340736f

typedef short short8 __attribute__((ext_vector_type(8)));
typedef float floatx4 __attribute__((ext_vector_type(4)));

template <int PAT>
__device__ __forceinline__ float swz(float v) {
  return __int_as_float(__builtin_amdgcn_ds_swizzle(__float_as_int(v), PAT));
}

// ---------------- CSR build ----------------
__global__ __launch_bounds__(256) void count_kernel(const int* __restrict__ ei,
                                                    int* __restrict__ cnt) {
  int idx = blockIdx.x * 256 + threadIdx.x;
  if (idx >= N_LAYERS * N_EDGES) return;
  int l = idx / N_EDGES, e = idx - l * N_EDGES;
  int dst = ei[(size_t)l * 2 * N_EDGES + N_EDGES + e];
  atomicAdd(&cnt[l * (N_NODES + 1) + dst], 1);
}

__global__ __launch_bounds__(1024) void scan_kernel(int* __restrict__ rowptr,
                                                    int* __restrict__ fillptr) {
  int l = blockIdx.x, t = threadIdx.x;
  int lane = t & 63, wv = t >> 6;  // 16 waves
  __shared__ int wsum[16];
  __shared__ int carry_s;
  if (t == 0) carry_s = 0;
  __syncthreads();
  int base = l * (N_NODES + 1);
  for (int c0 = 0; c0 < N_NODES; c0 += 1024) {
    int i = c0 + t;
    int v = (i < N_NODES) ? rowptr[base + i] : 0;
    int sc = v;
#pragma unroll
    for (int off = 1; off < 64; off <<= 1) {
      int u = __shfl_up(sc, off);
      if (lane >= off) sc += u;
    }
    if (lane == 63) wsum[wv] = sc;
    __syncthreads();
    if (wv == 0) {
      int xx = (lane < 16) ? wsum[lane] : 0;
#pragma unroll
      for (int off = 1; off < 16; off <<= 1) {
        int u = __shfl_up(xx, off);
        if (lane >= off) xx += u;
      }
      if (lane < 16) wsum[lane] = xx;
    }
    __syncthreads();
    int boff = carry_s + (wv > 0 ? wsum[wv - 1] : 0);
    int excl = boff + sc - v;
    if (i < N_NODES) { rowptr[base + i] = excl; fillptr[l * N_NODES + i] = excl; }
    int tot = wsum[15];
    __syncthreads();
    if (t == 0) carry_s += tot;
    __syncthreads();
  }
  if (t == 0) rowptr[base + N_NODES] = carry_s;
}

__global__ __launch_bounds__(256) void fill_kernel(const int* __restrict__ ei,
                                                   const float* __restrict__ ew,
                                                   int* __restrict__ fillptr,
                                                   int2* __restrict__ ep) {
  int idx = blockIdx.x * 256 + threadIdx.x;
  if (idx >= N_LAYERS * N_EDGES) return;
  int l = idx / N_EDGES, e = idx - l * N_EDGES;
  int src = ei[(size_t)l * 2 * N_EDGES + e];
  int dst = ei[(size_t)l * 2 * N_EDGES + N_EDGES + e];
  int pos = atomicAdd(&fillptr[l * N_NODES + dst], 1);
  int2 rec;
  rec.x = src;
  rec.y = __float_as_int(ew[(size_t)l * N_EDGES + e]);
  ep[(size_t)l * N_EDGES + pos] = rec;
}

// ---------------- fused GAT layer (1 wave per (layer,node)) ----------------
__global__ __launch_bounds__(256) void attn_kernel(
    const float* __restrict__ x, const int* __restrict__ rowptr,
    const int2* __restrict__ ep,
    const float* __restrict__ Wl, const float* __restrict__ bl,
    const float* __restrict__ Wr, const float* __restrict__ br,
    const float* __restrict__ We, const float* __restrict__ att,
    const float* __restrict__ cbias, float* __restrict__ out_pre) {
  int wid = blockIdx.x * 4 + (threadIdx.x >> 6);
  int lane = threadIdx.x & 63;
  int l = wid / N_NODES, n = wid - l * N_NODES;

  float wlv[5];
#pragma unroll
  for (int k = 0; k < 5; k++) wlv[k] = Wl[(l * 5 + k) * 64 + lane];
  float blv = bl[l * 64 + lane];
  float wev = We[l * 64 + lane];
  float att2v = att[l * 64 + lane] * LOG2E;

  // own-node transforms (x[n*5+k] uniform -> scalar loads)
  float xrn = br[l * 64 + lane];
  float xln = blv;
#pragma unroll
  for (int k = 0; k < 5; k++) {
    float xk = x[n * 5 + k];
    xrn = fmaf(xk, Wr[(l * 5 + k) * 64 + lane], xrn);
    xln = fmaf(xk, wlv[k], xln);
  }

  int start = __builtin_amdgcn_readfirstlane(rowptr[l * (N_NODES + 1) + n]);
  int end   = __builtin_amdgcn_readfirstlane(rowptr[l * (N_NODES + 1) + n + 1]);
  int cnt = end - start;
  const int2* epl = ep + (size_t)l * N_EDGES;

  float ssum = 0.f, acc = 0.f, ewsum = 0.f;

  // 1-deep prefetch of edge records
  int src0 = 0; float w0 = 0.f;
  if (start < end) {
    int2 pr = epl[start];
    src0 = pr.x; w0 = __int_as_float(pr.y);
  }
  for (int e = start; e < end; e++) {
    int srcn = 0; float wn = 0.f;
    if (e + 1 < end) {
      int2 pr = epl[e + 1];
      srcn = pr.x; wn = __int_as_float(pr.y);
    }
    float xls = blv;
#pragma unroll
    for (int k = 0; k < 5; k++) xls = fmaf(x[src0 * 5 + k], wlv[k], xls);
    float v = fmaf(w0, wev, xrn) + xls;
    float lk = fmaxf(v, 0.2f * v);
    float p = lk * att2v;
    p += swz<0x041F>(p);
    p += swz<0x081F>(p);
    p += swz<0x101F>(p);
    p += swz<0x201F>(p);
    p += swz<0x401F>(p);
    float pe = exp2f(p);  // no max subtraction: |logit| small, fp32 exp safe
    ssum += pe;
    acc = fmaf(xls, pe, acc);
    ewsum += w0;
    src0 = srcn; w0 = wn;
  }
  // self loop: attr = mean of incoming edge attrs
  {
    float w = ewsum / fmaxf((float)cnt, 1.f);
    float v = fmaf(w, wev, xrn) + xln;
    float lk = fmaxf(v, 0.2f * v);
    float p = lk * att2v;
    p += swz<0x041F>(p);
    p += swz<0x081F>(p);
    p += swz<0x101F>(p);
    p += swz<0x201F>(p);
    p += swz<0x401F>(p);
    float pe = exp2f(p);
    ssum += pe;
    acc = fmaf(xln, pe, acc);
  }
  float outv = acc / (ssum * (float)(cnt + 1));
  float o2 = outv + __shfl_xor(outv, 32);
  if (lane < 32)
    out_pre[((size_t)l * N_NODES + n) * 32 + lane] = 0.5f * o2 + cbias[l * 32 + lane];
}

// ---------------- BatchNorm stats ----------------
__global__ __launch_bounds__(256) void stats_kernel(const float* __restrict__ out_pre,
                                                    float* __restrict__ gsum,
                                                    float* __restrict__ gsumsq) {
  int l = blockIdx.x >> 4, chunk = blockIdx.x & 15;
  int t = threadIdx.x;
  int c = t & 31, nsub = t >> 5;
  int n0 = chunk * 1250;
  float s1 = 0.f, s2 = 0.f;
  for (int n = n0 + nsub; n < n0 + 1250; n += 8) {
    float v = out_pre[((size_t)l * N_NODES + n) * 32 + c];
    s1 += v; s2 += v * v;
  }
  __shared__ float l1[256], l2[256];
  l1[t] = s1; l2[t] = s2;
  __syncthreads();
  for (int off = 128; off >= 32; off >>= 1) {
    if (t < off) { l1[t] += l1[t + off]; l2[t] += l2[t + off]; }
    __syncthreads();
  }
  if (t < 32) {
    atomicAdd(&gsum[l * 32 + t], l1[t]);
    atomicAdd(&gsumsq[l * 32 + t], l2[t]);
  }
}

// ---------------- normalize + leaky relu -> bf16 [L][NPAD][32] ----------------
__global__ __launch_bounds__(256) void norm_kernel(const float* __restrict__ out_pre,
                                                   const float* __restrict__ gsum,
                                                   const float* __restrict__ gsumsq,
                                                   const float* __restrict__ gamma,
                                                   const float* __restrict__ beta,
                                                   __hip_bfloat16* __restrict__ hn) {
  int idx = blockIdx.x * 256 + threadIdx.x;  // < 25*20000*32
  int l = idx / (N_NODES * 32);
  int rem = idx - l * (N_NODES * 32);
  int n = rem >> 5, c = rem & 31;
  float mu = gsum[l * 32 + c] * (1.f / N_NODES);
  float var = gsumsq[l * 32 + c] * (1.f / N_NODES) - mu * mu;
  float v = out_pre[idx];
  v = gamma[l * 32 + c] * (v - mu) * rsqrtf(var + EPS_BN) + beta[l * 32 + c];
  v = v > 0.f ? v : 0.01f * v;
  hn[((size_t)l * NPAD + n) * 32 + c] = (__hip_bfloat16)v;
}

// ---------------- W1 -> bf16 transposed [896][800] ----------------
__global__ void w1t_kernel(const float* __restrict__ W1, __hip_bfloat16* __restrict__ W1bT) {
  __shared__ float tile[32][33];
  int j0 = blockIdx.x * 32, k0 = blockIdx.y * 32;
  int tx = threadIdx.x, ty = threadIdx.y;  // (32,8)
#pragma unroll
  for (int i = 0; i < 4; i++) {
    int k = k0 + ty + i * 8, j = j0 + tx;
    tile[ty + i * 8][tx] = (j < 800) ? W1[k * 800 + j] : 0.f;
  }
  __syncthreads();
#pragma unroll
  for (int i = 0; i < 4; i++) {
    int j = j0 + ty + i * 8, k = k0 + tx;
    W1bT[(size_t)j * 800 + k] = (__hip_bfloat16)tile[tx][ty + i * 8];
  }
}

// ---------------- GEMM1: h[NPAD x 800] @ W1 -> relu -> bf16 h1 ----------------
__global__ __launch_bounds__(256) void gemm1_kernel(const short* __restrict__ hn,
                                                    const short* __restrict__ W1bT,
                                                    const float* __restrict__ b1,
                                                    __hip_bfloat16* __restrict__ h1b) {
  __shared__ __align__(16) short As[128 * 40];
  __shared__ __align__(16) short Bs[128 * 40];
  int t = threadIdx.x;
  int n0 = blockIdx.x * 128, m0 = blockIdx.y * 128;
  int wave = t >> 6, lane = t & 63;
  int wr = wave >> 1, wc = wave & 1;
  int mrow = lane & 15, quad = lane >> 4;
  floatx4 acc[4][4];
#pragma unroll
  for (int i = 0; i < 4; i++)
#pragma unroll
    for (int j = 0; j < 4; j++) acc[i][j] = (floatx4){0.f, 0.f, 0.f, 0.f};

  for (int kt = 0; kt < 25; kt++) {
#pragma unroll
    for (int i = 0; i < 2; i++) {
      int q = t + i * 256;
      int r = q >> 2, sub = q & 3;
      const int4* gA = (const int4*)(hn + ((size_t)kt * NPAD + m0 + r) * 32 + sub * 8);
      *(int4*)(&As[r * 40 + sub * 8]) = *gA;
      const int4* gB = (const int4*)(W1bT + (size_t)(n0 + r) * 800 + kt * 32 + sub * 8);
      *(int4*)(&Bs[r * 40 + sub * 8]) = *gB;
    }
    __syncthreads();
    short8 af[4], bfr[4];
#pragma unroll
    for (int i = 0; i < 4; i++)
      af[i] = *(const short8*)(&As[(wr * 64 + i * 16 + mrow) * 40 + quad * 8]);
#pragma unroll
    for (int j = 0; j < 4; j++)
      bfr[j] = *(const short8*)(&Bs[(wc * 64 + j * 16 + mrow) * 40 + quad * 8]);
#pragma unroll
    for (int i = 0; i < 4; i++)
#pragma unroll
      for (int j = 0; j < 4; j++)
        acc[i][j] = __builtin_amdgcn_mfma_f32_16x16x32_bf16(af[i], bfr[j], acc[i][j], 0, 0, 0);
    __syncthreads();
  }

#pragma unroll
  for (int i = 0; i < 4; i++) {
#pragma unroll
    for (int j = 0; j < 4; j++) {
#pragma unroll
      for (int r = 0; r < 4; r++) {
        int row = m0 + wr * 64 + i * 16 + quad * 4 + r;
        int col = n0 + wc * 64 + j * 16 + mrow;
        if (col < 800) {
          float v = acc[i][j][r] + b1[col];
          v = fmaxf(v, 0.f);
          h1b[(size_t)row * 800 + col] = (__hip_bfloat16)v;
        }
      }
    }
  }
}

// ---------------- GEMM2: h1[20000 x 800] @ W2[800 x 5] + b2 ----------------
__global__ __launch_bounds__(256) void gemm2_kernel(const __hip_bfloat16* __restrict__ h1b,
                                                    const float* __restrict__ W2,
                                                    const float* __restrict__ b2,
                                                    float* __restrict__ out) {
  int wid = blockIdx.x * 4 + (threadIdx.x >> 6);
  int lane = threadIdx.x & 63;
  if (wid >= N_NODES) return;
  const __hip_bfloat16* row = h1b + (size_t)wid * 800;
  float a[5] = {0.f, 0.f, 0.f, 0.f, 0.f};
  for (int k = lane * 2; k < 800; k += 128) {
    float a0 = (float)row[k], a1 = (float)row[k + 1];
#pragma unroll
    for (int j = 0; j < 5; j++) a[j] += a0 * W2[k * 5 + j] + a1 * W2[(k + 1) * 5 + j];
  }
#pragma unroll
  for (int j = 0; j < 5; j++) {
    a[j] += __shfl_xor(a[j], 32);
    a[j] += __shfl_xor(a[j], 16);
    a[j] += __shfl_xor(a[j], 8);
    a[j] += __shfl_xor(a[j], 4);
    a[j] += __shfl_xor(a[j], 2);
    a[j] += __shfl_xor(a[j], 1);
  }
  if (lane == 0) {
#pragma unroll
    for (int j = 0; j < 5; j++) out[wid * 5 + j] = a[j] + b2[j];
  }
}

extern "C" void kernel_launch(void* const* d_in, const int* in_sizes, int n_in,
                              void* d_out, int out_size, void* d_ws, size_t ws_size,
                              hipStream_t stream) {
  const float* x    = (const float*)d_in[0];
  const int*   ei   = (const int*)d_in[1];
  const float* ew   = (const float*)d_in[2];
  const float* Wl   = (const float*)d_in[3];
  const float* bl   = (const float*)d_in[4];
  const float* Wr   = (const float*)d_in[5];
  const float* br   = (const float*)d_in[6];
  const float* We   = (const float*)d_in[7];
  const float* att  = (const float*)d_in[8];
  const float* cb   = (const float*)d_in[9];
  const float* gam  = (const float*)d_in[10];
  const float* bet  = (const float*)d_in[11];
  const float* W1   = (const float*)d_in[12];
  const float* b1   = (const float*)d_in[13];
  const float* W2   = (const float*)d_in[14];
  const float* b2   = (const float*)d_in[15];

  char* ws = (char*)d_ws;
  size_t off = 0;
  auto alloc = [&](size_t bytes) {
    void* p = ws + off;
    off = (off + bytes + 255) & ~(size_t)255;
    return p;
  };
  int* rowptr  = (int*)alloc((size_t)N_LAYERS * (N_NODES + 1) * 4);
  int* fillptr = (int*)alloc((size_t)N_LAYERS * N_NODES * 4);
  int2* ep     = (int2*)alloc((size_t)N_LAYERS * N_EDGES * 8);
  float* out_pre = (float*)alloc((size_t)N_LAYERS * N_NODES * 32 * 4);
  float* gsum   = (float*)alloc(N_LAYERS * 32 * 4);
  float* gsumsq = (float*)alloc(N_LAYERS * 32 * 4);
  __hip_bfloat16* hn  = (__hip_bfloat16*)alloc((size_t)N_LAYERS * NPAD * 32 * 2);
  __hip_bfloat16* w1t = (__hip_bfloat16*)alloc((size_t)896 * 800 * 2);
  __hip_bfloat16* h1b = (__hip_bfloat16*)out_pre;  // alias: out_pre dead after norm_kernel

  hipMemsetAsync(rowptr, 0, (size_t)N_LAYERS * (N_NODES + 1) * 4, stream);
  hipMemsetAsync(gsum, 0, N_LAYERS * 32 * 4, stream);
  hipMemsetAsync(gsumsq, 0, N_LAYERS * 32 * 4, stream);

  int ecnt = N_LAYERS * N_EDGES;
  count_kernel<<<(ecnt + 255) / 256, 256, 0, stream>>>(ei, rowptr);
  scan_kernel<<<N_LAYERS, 1024, 0, stream>>>(rowptr, fillptr);
  fill_kernel<<<(ecnt + 255) / 256, 256, 0, stream>>>(ei, ew, fillptr, ep);
  attn_kernel<<<(N_LAYERS * N_NODES) / 4, 256, 0, stream>>>(
      x, rowptr, ep, Wl, bl, Wr, br, We, att, cb, out_pre);
  stats_kernel<<<N_LAYERS * 16, 256, 0, stream>>>(out_pre, gsum, gsumsq);
  norm_kernel<<<(N_LAYERS * N_NODES * 32) / 256, 256, 0, stream>>>(
      out_pre, gsum, gsumsq, gam, bet, hn);
  w1t_kernel<<<dim3(28, 25), dim3(32, 8), 0, stream>>>(W1, w1t);
  gemm1_kernel<<<dim3(7, 157), 256, 0, stream>>>(
      (const short*)hn, (const short*)w1t, b1, h1b);
  gemm2_kernel<<<5000, 256, 0, stream>>>(h1b, W2, b2, (float*)d_out);
}

// Round 3
// 798.033 us; speedup vs baseline: 1.1432x; 1.0451x over previous
//
#include <hip/hip_runtime.h>
#include <hip/hip_bf16.h>

#define N_NODES 20000
#define N_EDGES 100000
#define N_LAYERS 25
#define NPAD 20096   // 157*128
#define EPS_BN 1e-5f
#define LOG2E 1.44269504088896340736f

typedef short short8 __attribute__((ext_vector_type(8)));
typedef float floatx4 __attribute__((ext_vector_type(4)));

template <int PAT>
__device__ __forceinline__ float swz(float v) {
  return __int_as_float(__builtin_amdgcn_ds_swizzle(__float_as_int(v), PAT));
}

// attention edge weight: leaky-relu, per-head (32-lane) dot with att, exp2
__device__ __forceinline__ float edge_w(float xlv, float w, float wev, float xrn,
                                        float att2v) {
  float v = xlv + fmaf(w, wev, xrn);
  float lk = fmaxf(v, 0.2f * v);
  float p = lk * att2v;
  p += swz<0x041F>(p);
  p += swz<0x081F>(p);
  p += swz<0x101F>(p);
  p += swz<0x201F>(p);
  p += swz<0x401F>(p);
  return exp2f(p);  // no max-subtraction: logits small, softmax shift-invariant
}

// ---------------- CSR build ----------------
__global__ __launch_bounds__(256) void count_kernel(const int* __restrict__ ei,
                                                    int* __restrict__ cnt) {
  int idx = blockIdx.x * 256 + threadIdx.x;
  if (idx >= N_LAYERS * N_EDGES) return;
  int l = idx / N_EDGES, e = idx - l * N_EDGES;
  int dst = ei[(size_t)l * 2 * N_EDGES + N_EDGES + e];
  atomicAdd(&cnt[l * (N_NODES + 1) + dst], 1);
}

__global__ __launch_bounds__(1024) void scan_kernel(int* __restrict__ rowptr,
                                                    int* __restrict__ fillptr) {
  int l = blockIdx.x, t = threadIdx.x;
  int lane = t & 63, wv = t >> 6;  // 16 waves
  __shared__ int wsum[16];
  __shared__ int carry_s;
  if (t == 0) carry_s = 0;
  __syncthreads();
  int base = l * (N_NODES + 1);
  for (int c0 = 0; c0 < N_NODES; c0 += 1024) {
    int i = c0 + t;
    int v = (i < N_NODES) ? rowptr[base + i] : 0;
    int sc = v;
#pragma unroll
    for (int off = 1; off < 64; off <<= 1) {
      int u = __shfl_up(sc, off);
      if (lane >= off) sc += u;
    }
    if (lane == 63) wsum[wv] = sc;
    __syncthreads();
    if (wv == 0) {
      int xx = (lane < 16) ? wsum[lane] : 0;
#pragma unroll
      for (int off = 1; off < 16; off <<= 1) {
        int u = __shfl_up(xx, off);
        if (lane >= off) xx += u;
      }
      if (lane < 16) wsum[lane] = xx;
    }
    __syncthreads();
    int boff = carry_s + (wv > 0 ? wsum[wv - 1] : 0);
    int excl = boff + sc - v;
    if (i < N_NODES) { rowptr[base + i] = excl; fillptr[l * N_NODES + i] = excl; }
    int tot = wsum[15];
    __syncthreads();
    if (t == 0) carry_s += tot;
    __syncthreads();
  }
  if (t == 0) rowptr[base + N_NODES] = carry_s;
}

__global__ __launch_bounds__(256) void fill_kernel(const int* __restrict__ ei,
                                                   const float* __restrict__ ew,
                                                   int* __restrict__ fillptr,
                                                   int2* __restrict__ ep) {
  int idx = blockIdx.x * 256 + threadIdx.x;
  if (idx >= N_LAYERS * N_EDGES) return;
  int l = idx / N_EDGES, e = idx - l * N_EDGES;
  int src = ei[(size_t)l * 2 * N_EDGES + e];
  int dst = ei[(size_t)l * 2 * N_EDGES + N_EDGES + e];
  int pos = atomicAdd(&fillptr[l * N_NODES + dst], 1);
  int2 rec;
  rec.x = src;
  rec.y = __float_as_int(ew[(size_t)l * N_EDGES + e]);
  ep[(size_t)l * N_EDGES + pos] = rec;
}

// ---------------- precompute xl = x @ Wl + bl, [L][N][64] ----------------
__global__ __launch_bounds__(256) void xl_kernel(const float* __restrict__ x,
                                                 const float* __restrict__ Wl,
                                                 const float* __restrict__ bl,
                                                 float* __restrict__ xl) {
  int wid = blockIdx.x * 4 + (threadIdx.x >> 6);
  int lane = threadIdx.x & 63;
  int l = wid / N_NODES, n = wid - l * N_NODES;
  float acc = bl[l * 64 + lane];
#pragma unroll
  for (int k = 0; k < 5; k++)
    acc = fmaf(x[n * 5 + k], Wl[(l * 5 + k) * 64 + lane], acc);
  xl[(size_t)wid * 64 + lane] = acc;
}

// ---------------- fused GAT layer (1 wave per (layer,node)) ----------------
__global__ __launch_bounds__(256) void attn_kernel(
    const float* __restrict__ x, const float* __restrict__ xl,
    const int* __restrict__ rowptr, const int2* __restrict__ ep,
    const float* __restrict__ Wr, const float* __restrict__ br,
    const float* __restrict__ We, const float* __restrict__ att,
    const float* __restrict__ cbias, float* __restrict__ out_pre) {
  int wid = blockIdx.x * 4 + (threadIdx.x >> 6);
  int lane = threadIdx.x & 63;
  int l = wid / N_NODES, n = wid - l * N_NODES;

  const float* xlb = xl + (size_t)l * N_NODES * 64;
  float wev = We[l * 64 + lane];
  float att2v = att[l * 64 + lane] * LOG2E;

  // own-node: xr (recomputed) and xl (from precompute)
  float xrn = br[l * 64 + lane];
#pragma unroll
  for (int k = 0; k < 5; k++)
    xrn = fmaf(x[n * 5 + k], Wr[(l * 5 + k) * 64 + lane], xrn);
  float xln = xlb[n * 64 + lane];

  int start = __builtin_amdgcn_readfirstlane(rowptr[l * (N_NODES + 1) + n]);
  int end   = __builtin_amdgcn_readfirstlane(rowptr[l * (N_NODES + 1) + n + 1]);
  int cnt = end - start;
  int cnt64 = cnt < 64 ? cnt : 64;

  // batch-load up to 64 edge records: lane e holds ep[start+e]
  int rsrc = 0, rw = 0;
  if (lane < cnt64) {
    int2 rec = ep[(size_t)l * N_EDGES + start + lane];
    rsrc = rec.x;
    rw = rec.y;
  }

  float ssum = 0.f, acc = 0.f, ewsum = 0.f;

  if (cnt64 > 0) {
    int last = cnt64 - 1;
    int sA = __builtin_amdgcn_readlane(rsrc, 0);
    int sB = __builtin_amdgcn_readlane(rsrc, 1 < last ? 1 : last);
    float xa = xlb[sA * 64 + lane];
    float xb = xlb[sB * 64 + lane];
    for (int e = 0; e < cnt64; e += 2) {
      int i2 = e + 2 < last ? e + 2 : last;
      int i3 = e + 3 < last ? e + 3 : last;
      int sC = __builtin_amdgcn_readlane(rsrc, i2);
      int sD = __builtin_amdgcn_readlane(rsrc, i3);
      float xc = xlb[sC * 64 + lane];  // prefetch next pair
      float xd = xlb[sD * 64 + lane];
      float w0 = __int_as_float(__builtin_amdgcn_readlane(rw, e));
      float pe0 = edge_w(xa, w0, wev, xrn, att2v);
      ssum += pe0;
      acc = fmaf(xa, pe0, acc);
      ewsum += w0;
      if (e + 1 < cnt64) {
        float w1 = __int_as_float(__builtin_amdgcn_readlane(rw, e + 1));
        float pe1 = edge_w(xb, w1, wev, xrn, att2v);
        ssum += pe1;
        acc = fmaf(xb, pe1, acc);
        ewsum += w1;
      }
      xa = xc;
      xb = xd;
    }
  }
  // rare overflow path: in-degree > 64
  for (int e = start + 64; e < end; e++) {
    int2 rec = ep[(size_t)l * N_EDGES + e];
    int s = __builtin_amdgcn_readfirstlane(rec.x);
    float w = __int_as_float(__builtin_amdgcn_readfirstlane(rec.y));
    float xv = xlb[s * 64 + lane];
    float pe = edge_w(xv, w, wev, xrn, att2v);
    ssum += pe;
    acc = fmaf(xv, pe, acc);
    ewsum += w;
  }
  // self loop: attr = mean of incoming edge attrs
  {
    float w = ewsum / fmaxf((float)cnt, 1.f);
    float pe = edge_w(xln, w, wev, xrn, att2v);
    ssum += pe;
    acc = fmaf(xln, pe, acc);
  }
  float outv = acc / (ssum * (float)(cnt + 1));
  float o2 = outv + __shfl_xor(outv, 32);
  if (lane < 32)
    out_pre[((size_t)l * N_NODES + n) * 32 + lane] = 0.5f * o2 + cbias[l * 32 + lane];
}

// ---------------- BatchNorm stats ----------------
__global__ __launch_bounds__(256) void stats_kernel(const float* __restrict__ out_pre,
                                                    float* __restrict__ gsum,
                                                    float* __restrict__ gsumsq) {
  int l = blockIdx.x >> 4, chunk = blockIdx.x & 15;
  int t = threadIdx.x;
  int c = t & 31, nsub = t >> 5;
  int n0 = chunk * 1250;
  float s1 = 0.f, s2 = 0.f;
  for (int n = n0 + nsub; n < n0 + 1250; n += 8) {
    float v = out_pre[((size_t)l * N_NODES + n) * 32 + c];
    s1 += v; s2 += v * v;
  }
  __shared__ float l1[256], l2[256];
  l1[t] = s1; l2[t] = s2;
  __syncthreads();
  for (int off = 128; off >= 32; off >>= 1) {
    if (t < off) { l1[t] += l1[t + off]; l2[t] += l2[t + off]; }
    __syncthreads();
  }
  if (t < 32) {
    atomicAdd(&gsum[l * 32 + t], l1[t]);
    atomicAdd(&gsumsq[l * 32 + t], l2[t]);
  }
}

// ---------------- normalize + leaky relu -> bf16 [L][NPAD][32] ----------------
__global__ __launch_bounds__(256) void norm_kernel(const float* __restrict__ out_pre,
                                                   const float* __restrict__ gsum,
                                                   const float* __restrict__ gsumsq,
                                                   const float* __restrict__ gamma,
                                                   const float* __restrict__ beta,
                                                   __hip_bfloat16* __restrict__ hn) {
  int idx = blockIdx.x * 256 + threadIdx.x;  // < 25*20000*32
  int l = idx / (N_NODES * 32);
  int rem = idx - l * (N_NODES * 32);
  int n = rem >> 5, c = rem & 31;
  float mu = gsum[l * 32 + c] * (1.f / N_NODES);
  float var = gsumsq[l * 32 + c] * (1.f / N_NODES) - mu * mu;
  float v = out_pre[idx];
  v = gamma[l * 32 + c] * (v - mu) * rsqrtf(var + EPS_BN) + beta[l * 32 + c];
  v = v > 0.f ? v : 0.01f * v;
  hn[((size_t)l * NPAD + n) * 32 + c] = (__hip_bfloat16)v;
}

// ---------------- W1 -> bf16 transposed [896][800] ----------------
__global__ void w1t_kernel(const float* __restrict__ W1, __hip_bfloat16* __restrict__ W1bT) {
  __shared__ float tile[32][33];
  int j0 = blockIdx.x * 32, k0 = blockIdx.y * 32;
  int tx = threadIdx.x, ty = threadIdx.y;  // (32,8)
#pragma unroll
  for (int i = 0; i < 4; i++) {
    int k = k0 + ty + i * 8, j = j0 + tx;
    tile[ty + i * 8][tx] = (j < 800) ? W1[k * 800 + j] : 0.f;
  }
  __syncthreads();
#pragma unroll
  for (int i = 0; i < 4; i++) {
    int j = j0 + ty + i * 8, k = k0 + tx;
    W1bT[(size_t)j * 800 + k] = (__hip_bfloat16)tile[tx][ty + i * 8];
  }
}

// ---------------- GEMM1: h[NPAD x 800] @ W1 -> relu -> bf16 h1 ----------------
__global__ __launch_bounds__(256) void gemm1_kernel(const short* __restrict__ hn,
                                                    const short* __restrict__ W1bT,
                                                    const float* __restrict__ b1,
                                                    __hip_bfloat16* __restrict__ h1b) {
  __shared__ __align__(16) short As[128 * 40];
  __shared__ __align__(16) short Bs[128 * 40];
  int t = threadIdx.x;
  int n0 = blockIdx.x * 128, m0 = blockIdx.y * 128;
  int wave = t >> 6, lane = t & 63;
  int wr = wave >> 1, wc = wave & 1;
  int mrow = lane & 15, quad = lane >> 4;
  floatx4 acc[4][4];
#pragma unroll
  for (int i = 0; i < 4; i++)
#pragma unroll
    for (int j = 0; j < 4; j++) acc[i][j] = (floatx4){0.f, 0.f, 0.f, 0.f};

  for (int kt = 0; kt < 25; kt++) {
#pragma unroll
    for (int i = 0; i < 2; i++) {
      int q = t + i * 256;
      int r = q >> 2, sub = q & 3;
      const int4* gA = (const int4*)(hn + ((size_t)kt * NPAD + m0 + r) * 32 + sub * 8);
      *(int4*)(&As[r * 40 + sub * 8]) = *gA;
      const int4* gB = (const int4*)(W1bT + (size_t)(n0 + r) * 800 + kt * 32 + sub * 8);
      *(int4*)(&Bs[r * 40 + sub * 8]) = *gB;
    }
    __syncthreads();
    short8 af[4], bfr[4];
#pragma unroll
    for (int i = 0; i < 4; i++)
      af[i] = *(const short8*)(&As[(wr * 64 + i * 16 + mrow) * 40 + quad * 8]);
#pragma unroll
    for (int j = 0; j < 4; j++)
      bfr[j] = *(const short8*)(&Bs[(wc * 64 + j * 16 + mrow) * 40 + quad * 8]);
#pragma unroll
    for (int i = 0; i < 4; i++)
#pragma unroll
      for (int j = 0; j < 4; j++)
        acc[i][j] = __builtin_amdgcn_mfma_f32_16x16x32_bf16(af[i], bfr[j], acc[i][j], 0, 0, 0);
    __syncthreads();
  }

#pragma unroll
  for (int i = 0; i < 4; i++) {
#pragma unroll
    for (int j = 0; j < 4; j++) {
#pragma unroll
      for (int r = 0; r < 4; r++) {
        int row = m0 + wr * 64 + i * 16 + quad * 4 + r;
        int col = n0 + wc * 64 + j * 16 + mrow;
        if (col < 800) {
          float v = acc[i][j][r] + b1[col];
          v = fmaxf(v, 0.f);
          h1b[(size_t)row * 800 + col] = (__hip_bfloat16)v;
        }
      }
    }
  }
}

// ---------------- GEMM2: h1[20000 x 800] @ W2[800 x 5] + b2 ----------------
__global__ __launch_bounds__(256) void gemm2_kernel(const __hip_bfloat16* __restrict__ h1b,
                                                    const float* __restrict__ W2,
                                                    const float* __restrict__ b2,
                                                    float* __restrict__ out) {
  int wid = blockIdx.x * 4 + (threadIdx.x >> 6);
  int lane = threadIdx.x & 63;
  if (wid >= N_NODES) return;
  const __hip_bfloat16* row = h1b + (size_t)wid * 800;
  float a[5] = {0.f, 0.f, 0.f, 0.f, 0.f};
  for (int k = lane * 2; k < 800; k += 128) {
    float a0 = (float)row[k], a1 = (float)row[k + 1];
#pragma unroll
    for (int j = 0; j < 5; j++) a[j] += a0 * W2[k * 5 + j] + a1 * W2[(k + 1) * 5 + j];
  }
#pragma unroll
  for (int j = 0; j < 5; j++) {
    a[j] += __shfl_xor(a[j], 32);
    a[j] += __shfl_xor(a[j], 16);
    a[j] += __shfl_xor(a[j], 8);
    a[j] += __shfl_xor(a[j], 4);
    a[j] += __shfl_xor(a[j], 2);
    a[j] += __shfl_xor(a[j], 1);
  }
  if (lane == 0) {
#pragma unroll
    for (int j = 0; j < 5; j++) out[wid * 5 + j] = a[j] + b2[j];
  }
}

extern "C" void kernel_launch(void* const* d_in, const int* in_sizes, int n_in,
                              void* d_out, int out_size, void* d_ws, size_t ws_size,
                              hipStream_t stream) {
  const float* x    = (const float*)d_in[0];
  const int*   ei   = (const int*)d_in[1];
  const float* ew   = (const float*)d_in[2];
  const float* Wl   = (const float*)d_in[3];
  const float* bl   = (const float*)d_in[4];
  const float* Wr   = (const float*)d_in[5];
  const float* br   = (const float*)d_in[6];
  const float* We   = (const float*)d_in[7];
  const float* att  = (const float*)d_in[8];
  const float* cb   = (const float*)d_in[9];
  const float* gam  = (const float*)d_in[10];
  const float* bet  = (const float*)d_in[11];
  const float* W1   = (const float*)d_in[12];
  const float* b1   = (const float*)d_in[13];
  const float* W2   = (const float*)d_in[14];
  const float* b2   = (const float*)d_in[15];

  char* ws = (char*)d_ws;
  size_t off = 0;
  auto alloc = [&](size_t bytes) {
    void* p = ws + off;
    off = (off + bytes + 255) & ~(size_t)255;
    return p;
  };
  int* rowptr  = (int*)alloc((size_t)N_LAYERS * (N_NODES + 1) * 4);
  int* fillptr = (int*)alloc((size_t)N_LAYERS * N_NODES * 4);
  int2* ep     = (int2*)alloc((size_t)N_LAYERS * N_EDGES * 8);
  float* out_pre = (float*)alloc((size_t)N_LAYERS * N_NODES * 32 * 4);
  float* gsum   = (float*)alloc(N_LAYERS * 32 * 4);
  float* gsumsq = (float*)alloc(N_LAYERS * 32 * 4);
  float* xl     = (float*)alloc((size_t)N_LAYERS * N_NODES * 64 * 4);  // 128 MB
  __hip_bfloat16* w1t = (__hip_bfloat16*)alloc((size_t)896 * 800 * 2);
  __hip_bfloat16* hn  = (__hip_bfloat16*)xl;       // alias: xl dead after attn
  __hip_bfloat16* h1b = (__hip_bfloat16*)out_pre;  // alias: out_pre dead after norm

  hipMemsetAsync(rowptr, 0, (size_t)N_LAYERS * (N_NODES + 1) * 4, stream);
  hipMemsetAsync(gsum, 0, N_LAYERS * 32 * 4, stream);
  hipMemsetAsync(gsumsq, 0, N_LAYERS * 32 * 4, stream);

  int ecnt = N_LAYERS * N_EDGES;
  count_kernel<<<(ecnt + 255) / 256, 256, 0, stream>>>(ei, rowptr);
  scan_kernel<<<N_LAYERS, 1024, 0, stream>>>(rowptr, fillptr);
  fill_kernel<<<(ecnt + 255) / 256, 256, 0, stream>>>(ei, ew, fillptr, ep);
  xl_kernel<<<(N_LAYERS * N_NODES) / 4, 256, 0, stream>>>(x, Wl, bl, xl);
  attn_kernel<<<(N_LAYERS * N_NODES) / 4, 256, 0, stream>>>(
      x, xl, rowptr, ep, Wr, br, We, att, cb, out_pre);
  stats_kernel<<<N_LAYERS * 16, 256, 0, stream>>>(out_pre, gsum, gsumsq);
  norm_kernel<<<(N_LAYERS * N_NODES * 32) / 256, 256, 0, stream>>>(
      out_pre, gsum, gsumsq, gam, bet, hn);
  w1t_kernel<<<dim3(28, 25), dim3(32, 8), 0, stream>>>(W1, w1t);
  gemm1_kernel<<<dim3(7, 157), 256, 0, stream>>>(
      (const short*)hn, (const short*)w1t, b1, h1b);
  gemm2_kernel<<<5000, 256, 0, stream>>>(h1b, W2, b2, (float*)d_out);
}